// Round 11
// baseline (84.878 us; speedup 1.0000x reference)
//
#include <hip/hip_runtime.h>

#define N_NODES 10000
#define E_EDGES 640000
#define C 128
#define NBA 32            // deg-partial blocks (edge blocks in k_deg)
#define NBS 64            // ta/tb partial blocks
#define NBC 63            // greduce blocks (63*160 = 10080 >= 10000)
#define CCH 160           // nodes per greduce block

typedef float vf4 __attribute__((ext_vector_type(4)));

// Native LDS fp32 add: relaxed, workgroup scope -> ds_add_f32 (no CAS loop).
__device__ __forceinline__ void lds_add(float* p, float v) {
    __hip_atomic_fetch_add(p, v, __ATOMIC_RELAXED, __HIP_MEMORY_SCOPE_WORKGROUP);
}

// ---------------- k1: deg partials; aux block: s1 + zero g/ctrl ----------------
__global__ __launch_bounds__(512) void k_deg(const int* __restrict__ col,
                                             const float* __restrict__ w,
                                             const float* __restrict__ W1,
                                             float* __restrict__ degp,
                                             float* __restrict__ s1,
                                             float* __restrict__ g,
                                             unsigned* __restrict__ ctrl) {
    const int tid = threadIdx.x, bid = blockIdx.x;
    if (bid == NBA) {                                     // aux block
        if (tid < C) {
            float s = 0.0f;
            #pragma unroll 16
            for (int k = 0; k < C; ++k) s += W1[k * C + tid];  // coalesced
            s1[tid] = s;
            g[tid]  = 0.0f;
        }
        if (tid == 0) *ctrl = 0u;
        return;
    }
    __shared__ float sdeg[N_NODES];                       // 40 KB
    vf4 z = {0.f, 0.f, 0.f, 0.f};
    for (int i = tid; i < N_NODES / 4; i += 512) ((vf4*)sdeg)[i] = z;
    __syncthreads();
    const int epb = E_EDGES / NBA;                        // 20000
    const int4*   col4 = (const int4*)(col + bid * epb);
    const float4* w4   = (const float4*)(w + bid * epb);
    for (int k = tid; k < epb / 4; k += 512) {
        int4 cc = col4[k]; float4 ww = w4[k];
        lds_add(&sdeg[cc.x], ww.x);
        lds_add(&sdeg[cc.y], ww.y);
        lds_add(&sdeg[cc.z], ww.z);
        lds_add(&sdeg[cc.w], ww.w);
    }
    __syncthreads();
    float* dst = degp + (size_t)bid * N_NODES;
    for (int i = tid; i < N_NODES / 4; i += 512)
        ((vf4*)dst)[i] = ((const vf4*)sdeg)[i];           // plain coalesced flush
}

// ---------------- k2: redundant deg-fold -> LDS dinv; ta/tb LDS scatter ------------
__global__ __launch_bounds__(512) void k_scatter(const int* __restrict__ row,
                                                 const int* __restrict__ col,
                                                 const float* __restrict__ w,
                                                 const float* __restrict__ degp,
                                                 float* __restrict__ tap,
                                                 float* __restrict__ tbp) {
    __shared__ float sta[N_NODES];                        // 40 KB
    __shared__ float stb[N_NODES];                        // 40 KB
    __shared__ float sdv[N_NODES];                        // 40 KB -> 117 KB, 1 blk/CU
    const int tid = threadIdx.x, bid = blockIdx.x;
    vf4 z = {0.f, 0.f, 0.f, 0.f};
    for (int i = tid; i < N_NODES / 4; i += 512) { ((vf4*)sta)[i] = z; ((vf4*)stb)[i] = z; }
    for (int i = tid; i < N_NODES / 4; i += 512) {        // fold deg -> dinv (vec4)
        vf4 d = {1.f, 1.f, 1.f, 1.f};                     // self-loop weight
        #pragma unroll 8
        for (int b = 0; b < NBA; ++b)
            d += ((const vf4*)(degp + (size_t)b * N_NODES))[i];
        vf4 r;
        r.x = rsqrtf(d.x); r.y = rsqrtf(d.y); r.z = rsqrtf(d.z); r.w = rsqrtf(d.w);
        ((vf4*)sdv)[i] = r;
    }
    __syncthreads();
    const int epb = E_EDGES / NBS;                        // 10000
    const int4*   row4 = (const int4*)(row + bid * epb);
    const int4*   col4 = (const int4*)(col + bid * epb);
    const float4* w4   = (const float4*)(w + bid * epb);
    for (int k = tid; k < epb / 4; k += 512) {
        int4 rr = row4[k]; int4 cc = col4[k]; float4 ww = w4[k];
        float dr0 = sdv[rr.x], dc0 = sdv[cc.x];           // LDS gathers
        float dr1 = sdv[rr.y], dc1 = sdv[cc.y];
        float dr2 = sdv[rr.z], dc2 = sdv[cc.z];
        float dr3 = sdv[rr.w], dc3 = sdv[cc.w];
        lds_add(&sta[cc.x], ww.x * dr0);
        lds_add(&stb[rr.x], ww.x * dc0);
        lds_add(&sta[cc.y], ww.y * dr1);
        lds_add(&stb[rr.y], ww.y * dc1);
        lds_add(&sta[cc.z], ww.z * dr2);
        lds_add(&stb[rr.z], ww.z * dc2);
        lds_add(&sta[cc.w], ww.w * dr3);
        lds_add(&stb[rr.w], ww.w * dc3);
    }
    __syncthreads();
    float* da = tap + (size_t)bid * N_NODES;
    float* db = tbp + (size_t)bid * N_NODES;
    for (int i = tid; i < N_NODES / 4; i += 512) {
        ((vf4*)da)[i] = ((const vf4*)sta)[i];
        ((vf4*)db)[i] = ((const vf4*)stb)[i];
    }
}

// ---------------- k3: fold -> alpha/beta, channel reduce, g atomics, gated final ----
__global__ __launch_bounds__(512) void k_greduce(const float* __restrict__ tap,
                                                 const float* __restrict__ tbp,
                                                 const float* __restrict__ degp,
                                                 const float* __restrict__ s1,
                                                 const float* __restrict__ b1,
                                                 const float* __restrict__ W2,
                                                 const float* __restrict__ b2,
                                                 float* __restrict__ g,
                                                 unsigned* __restrict__ ctrl,
                                                 float* __restrict__ out) {
    __shared__ float sal[CCH], sbe[CCH], sp[512];
    __shared__ int lastFlag;
    const int tid = threadIdx.x, bid = blockIdx.x;
    const int i0 = bid * CCH;
    int n = N_NODES - i0;
    n = n < 0 ? 0 : (n > CCH ? CCH : n);
    if (tid < n) {                                        // fold t_a + deg -> alpha
        int i = i0 + tid;
        float ta = 0.0f, d = 1.0f;
        #pragma unroll 16
        for (int b = 0; b < NBS; ++b) ta += tap[(size_t)b * N_NODES + i];
        #pragma unroll 8
        for (int b = 0; b < NBA; ++b) d += degp[(size_t)b * N_NODES + i];
        float di = rsqrtf(d);
        sal[tid] = fmaf(di, ta, di * di);
    } else if (tid >= 256 && tid - 256 < n) {             // fold t_b + deg -> beta
        int t = tid - 256;
        int i = i0 + t;
        float tb = 0.0f, d = 1.0f;
        #pragma unroll 16
        for (int b = 0; b < NBS; ++b) tb += tbp[(size_t)b * N_NODES + i];
        #pragma unroll 8
        for (int b = 0; b < NBA; ++b) d += degp[(size_t)b * N_NODES + i];
        float di = rsqrtf(d);
        sbe[t] = fmaf(di, tb, di * di);
    }
    __syncthreads();
    const int j   = tid & (C - 1);
    const int sub = tid >> 7;                             // 4 channel-subsets
    float s1j = s1[j], b1j = b1[j], acc = 0.0f;
    for (int t = sub; t < n; t += 4) {                    // LDS broadcast reads
        float h = fmaf(sal[t], s1j, b1j);
        acc += sbe[t] * fmaxf(h, 0.0f);                   // exact relu
    }
    sp[tid] = acc;
    __syncthreads();
    if (tid < C) {
        float G = sp[tid] + sp[tid + 128] + sp[tid + 256] + sp[tid + 384];
        unsafeAtomicAdd(&g[tid], G);                      // native global fadd
    }
    // ---- non-blocking last-block gate (no spin; validated R9/R10) ----
    __syncthreads();                                      // all g-atomics issued
    if (tid == 0) {
        unsigned old = __hip_atomic_fetch_add(ctrl, 1u, __ATOMIC_ACQ_REL,
                                              __HIP_MEMORY_SCOPE_AGENT);
        lastFlag = (old == NBC - 1);
        if (lastFlag) __builtin_amdgcn_fence(__ATOMIC_ACQUIRE, "agent");
    }
    __syncthreads();
    if (lastFlag) {
        float a2 = 0.0f;
        #pragma unroll
        for (int k = sub * 32; k < sub * 32 + 32; ++k)
            a2 += g[k] * W2[k * C + j];                   // g broadcast, W2 coalesced
        sp[tid] = a2;
        __syncthreads();
        if (tid < C) {
            float r = sp[tid] + sp[tid + 128] + sp[tid + 256] + sp[tid + 384];
            out[tid] = r * (1.0f / (float)N_NODES) + b2[tid];
        }
    }
}

extern "C" void kernel_launch(void* const* d_in, const int* in_sizes, int n_in,
                              void* d_out, int out_size, void* d_ws, size_t ws_size,
                              hipStream_t stream) {
    const int*   eidx = (const int*)d_in[1];
    const int*   row  = eidx;             // edge_index[0]
    const int*   col  = eidx + E_EDGES;   // edge_index[1]
    const float* w    = (const float*)d_in[2];
    const float* W1   = (const float*)d_in[3];
    const float* b1   = (const float*)d_in[4];
    const float* W2   = (const float*)d_in[5];
    const float* b2   = (const float*)d_in[6];
    float* out = (float*)d_out;
    float* ws  = (float*)d_ws;

    float*    degp = ws;                                  // NBA * N
    float*    tap  = degp + (size_t)NBA * N_NODES;        // NBS * N
    float*    tbp  = tap  + (size_t)NBS * N_NODES;        // NBS * N
    float*    s1   = tbp  + (size_t)NBS * N_NODES;        // C
    float*    g    = s1 + C;                              // C
    unsigned* ctrl = (unsigned*)(g + C);                  // 1 counter

    k_deg    <<<NBA + 1, 512, 0, stream>>>(col, w, W1, degp, s1, g, ctrl);
    k_scatter<<<NBS, 512, 0, stream>>>(row, col, w, degp, tap, tbp);
    k_greduce<<<NBC, 512, 0, stream>>>(tap, tbp, degp, s1, b1, W2, b2, g, ctrl, out);
}

// Round 12
// 49.244 us; speedup vs baseline: 1.7236x; 1.7236x over previous
//
#include <hip/hip_runtime.h>

#define N_NODES 10000
#define E_EDGES 640000
#define C 128
#define NBA 128           // deg-partial blocks
#define NBS 128           // ta partial blocks (same count for tb)
#define NBC 63            // greduce blocks (63*160 = 10080 >= 10000)
#define CCH 160           // nodes per greduce block

typedef float vf4 __attribute__((ext_vector_type(4)));

// Native LDS fp32 add: relaxed, workgroup scope -> ds_add_f32 (no CAS loop).
__device__ __forceinline__ void lds_add(float* p, float v) {
    __hip_atomic_fetch_add(p, v, __ATOMIC_RELAXED, __HIP_MEMORY_SCOPE_WORKGROUP);
}

// ---------------- k1: deg partials (LDS scatter by col) ----------------
__global__ __launch_bounds__(512) void k_deg(const int* __restrict__ col,
                                             const float* __restrict__ w,
                                             float* __restrict__ degp) {
    __shared__ float sdeg[N_NODES];                       // 40 KB, 4 blk/CU
    const int tid = threadIdx.x, bid = blockIdx.x;
    vf4 z = {0.f, 0.f, 0.f, 0.f};
    for (int i = tid; i < N_NODES / 4; i += 512) ((vf4*)sdeg)[i] = z;
    __syncthreads();
    const int epb = E_EDGES / NBA;                        // 5000
    const int4*   col4 = (const int4*)(col + bid * epb);
    const float4* w4   = (const float4*)(w + bid * epb);
    for (int k = tid; k < epb / 4; k += 512) {
        int4 cc = col4[k]; float4 ww = w4[k];
        lds_add(&sdeg[cc.x], ww.x);
        lds_add(&sdeg[cc.y], ww.y);
        lds_add(&sdeg[cc.z], ww.z);
        lds_add(&sdeg[cc.w], ww.w);
    }
    __syncthreads();
    float* dst = degp + (size_t)bid * N_NODES;
    for (int i = tid; i < N_NODES / 4; i += 512)
        ((vf4*)dst)[i] = ((const vf4*)sdeg)[i];           // plain coalesced flush
}

// -------- k2: fold deg -> dinv; block 0 also computes s1 and zeroes g/ctrl --------
__global__ __launch_bounds__(256) void k_dinv(const float* __restrict__ degp,
                                              float* __restrict__ dinv,
                                              const float* __restrict__ W1,
                                              float* __restrict__ s1,
                                              float* __restrict__ g,
                                              unsigned* __restrict__ ctrl) {
    int i = blockIdx.x * 256 + threadIdx.x;
    if (i < N_NODES) {
        float d = 1.0f;                                   // self-loop weight
        #pragma unroll 16
        for (int b = 0; b < NBA; ++b) d += degp[(size_t)b * N_NODES + i];
        dinv[i] = rsqrtf(d);
    }
    if (blockIdx.x == 0) {
        if (threadIdx.x < C) {
            int j = threadIdx.x;
            float s = 0.0f;
            #pragma unroll 16
            for (int k = 0; k < C; ++k) s += W1[k * C + j];   // coalesced across j
            s1[j] = s;
            g[j]  = 0.0f;
        }
        if (threadIdx.x == 0) *ctrl = 0u;
    }
}

// ------ k3: split halves. Blocks [0,NBS): t_a (by col); [NBS,2*NBS): t_b (by row) ----
__global__ __launch_bounds__(512) void k_scatter(const int* __restrict__ row,
                                                 const int* __restrict__ col,
                                                 const float* __restrict__ w,
                                                 const float* __restrict__ dinv,
                                                 float* __restrict__ tap,
                                                 float* __restrict__ tbp) {
    __shared__ float st[N_NODES];                         // 40 KB, 4 blk/CU
    const int tid = threadIdx.x;
    const bool isA = blockIdx.x < NBS;
    const int bid  = isA ? blockIdx.x : blockIdx.x - NBS;
    vf4 z = {0.f, 0.f, 0.f, 0.f};
    for (int i = tid; i < N_NODES / 4; i += 512) ((vf4*)st)[i] = z;
    __syncthreads();
    const int epb = E_EDGES / NBS;                        // 5000
    const int4*   row4 = (const int4*)(row + bid * epb);
    const int4*   col4 = (const int4*)(col + bid * epb);
    const float4* w4   = (const float4*)(w + bid * epb);
    if (isA) {                                            // t_a[c] += w * dinv[r]
        for (int k = tid; k < epb / 4; k += 512) {
            int4 rr = row4[k]; int4 cc = col4[k]; float4 ww = w4[k];
            lds_add(&st[cc.x], ww.x * dinv[rr.x]);
            lds_add(&st[cc.y], ww.y * dinv[rr.y]);
            lds_add(&st[cc.z], ww.z * dinv[rr.z]);
            lds_add(&st[cc.w], ww.w * dinv[rr.w]);
        }
    } else {                                              // t_b[r] += w * dinv[c]
        for (int k = tid; k < epb / 4; k += 512) {
            int4 rr = row4[k]; int4 cc = col4[k]; float4 ww = w4[k];
            lds_add(&st[rr.x], ww.x * dinv[cc.x]);
            lds_add(&st[rr.y], ww.y * dinv[cc.y]);
            lds_add(&st[rr.z], ww.z * dinv[cc.z]);
            lds_add(&st[rr.w], ww.w * dinv[cc.w]);
        }
    }
    __syncthreads();
    float* dst = (isA ? tap : tbp) + (size_t)bid * N_NODES;
    for (int i = tid; i < N_NODES / 4; i += 512)
        ((vf4*)dst)[i] = ((const vf4*)st)[i];             // coalesced flush
}

// ---------------- k4: fold -> alpha/beta, channel reduce, g atomics, gated final ----
__global__ __launch_bounds__(512) void k_greduce(const float* __restrict__ tap,
                                                 const float* __restrict__ tbp,
                                                 const float* __restrict__ dinv,
                                                 const float* __restrict__ s1,
                                                 const float* __restrict__ b1,
                                                 const float* __restrict__ W2,
                                                 const float* __restrict__ b2,
                                                 float* __restrict__ g,
                                                 unsigned* __restrict__ ctrl,
                                                 float* __restrict__ out) {
    __shared__ float sal[CCH], sbe[CCH], sp[512];
    __shared__ int lastFlag;
    const int tid = threadIdx.x, bid = blockIdx.x;
    const int i0 = bid * CCH;
    int n = N_NODES - i0;
    n = n < 0 ? 0 : (n > CCH ? CCH : n);
    if (tid < n) {                                        // fold t_a -> alpha
        int i = i0 + tid;
        float ta = 0.0f;
        #pragma unroll 16
        for (int b = 0; b < NBS; ++b) ta += tap[(size_t)b * N_NODES + i];
        float di = dinv[i];
        sal[tid] = fmaf(di, ta, di * di);
    } else if (tid >= 256 && tid - 256 < n) {             // fold t_b -> beta (parallel)
        int t = tid - 256;
        int i = i0 + t;
        float tb = 0.0f;
        #pragma unroll 16
        for (int b = 0; b < NBS; ++b) tb += tbp[(size_t)b * N_NODES + i];
        float di = dinv[i];
        sbe[t] = fmaf(di, tb, di * di);
    }
    __syncthreads();
    const int j   = tid & (C - 1);
    const int sub = tid >> 7;                             // 4 channel-subsets
    float s1j = s1[j], b1j = b1[j], acc = 0.0f;
    for (int t = sub; t < n; t += 4) {                    // LDS broadcast reads
        float h = fmaf(sal[t], s1j, b1j);
        acc += sbe[t] * fmaxf(h, 0.0f);                   // exact relu
    }
    sp[tid] = acc;
    __syncthreads();
    if (tid < C) {
        float G = sp[tid] + sp[tid + 128] + sp[tid + 256] + sp[tid + 384];
        unsafeAtomicAdd(&g[tid], G);                      // native global fadd
    }
    // ---- non-blocking last-block gate (no spin; validated R9/R10) ----
    __syncthreads();                                      // all g-atomics issued
    if (tid == 0) {
        unsigned old = __hip_atomic_fetch_add(ctrl, 1u, __ATOMIC_ACQ_REL,
                                              __HIP_MEMORY_SCOPE_AGENT);
        lastFlag = (old == NBC - 1);
        if (lastFlag) __builtin_amdgcn_fence(__ATOMIC_ACQUIRE, "agent");
    }
    __syncthreads();
    if (lastFlag) {
        float a2 = 0.0f;
        #pragma unroll
        for (int k = sub * 32; k < sub * 32 + 32; ++k)
            a2 += g[k] * W2[k * C + j];                   // g broadcast, W2 coalesced
        sp[tid] = a2;
        __syncthreads();
        if (tid < C) {
            float r = sp[tid] + sp[tid + 128] + sp[tid + 256] + sp[tid + 384];
            out[tid] = r * (1.0f / (float)N_NODES) + b2[tid];
        }
    }
}

extern "C" void kernel_launch(void* const* d_in, const int* in_sizes, int n_in,
                              void* d_out, int out_size, void* d_ws, size_t ws_size,
                              hipStream_t stream) {
    const int*   eidx = (const int*)d_in[1];
    const int*   row  = eidx;             // edge_index[0]
    const int*   col  = eidx + E_EDGES;   // edge_index[1]
    const float* w    = (const float*)d_in[2];
    const float* W1   = (const float*)d_in[3];
    const float* b1   = (const float*)d_in[4];
    const float* W2   = (const float*)d_in[5];
    const float* b2   = (const float*)d_in[6];
    float* out = (float*)d_out;
    float* ws  = (float*)d_ws;

    float*    degp = ws;                                  // NBA * N
    float*    tap  = degp + (size_t)NBA * N_NODES;        // NBS * N
    float*    tbp  = tap  + (size_t)NBS * N_NODES;        // NBS * N
    float*    dinv = tbp  + (size_t)NBS * N_NODES;        // N
    float*    s1   = dinv + N_NODES;                      // C
    float*    g    = s1 + C;                              // C
    unsigned* ctrl = (unsigned*)(g + C);                  // 1 counter

    k_deg    <<<NBA, 512, 0, stream>>>(col, w, degp);
    k_dinv   <<<(N_NODES + 255) / 256, 256, 0, stream>>>(degp, dinv, W1, s1, g, ctrl);
    k_scatter<<<2 * NBS, 512, 0, stream>>>(row, col, w, dinv, tap, tbp);
    k_greduce<<<NBC, 512, 0, stream>>>(tap, tbp, dinv, s1, b1, W2, b2, g, ctrl, out);
}